// Round 13
// baseline (290.547 us; speedup 1.0000x reference)
//
#include <hip/hip_runtime.h>
#include <math.h>

#define B_ 8
#define N_ 4096
#define D_ 1024
#define E_ 64
#define T_ 128

using bf16   = __bf16;
using bf16x4 = __attribute__((ext_vector_type(4))) __bf16;
using bf16x8 = __attribute__((ext_vector_type(8))) __bf16;
using f32x4  = __attribute__((ext_vector_type(4))) float;

#define MFMA16(a, b, c) __builtin_amdgcn_mfma_f32_16x16x32_bf16(a, b, c, 0, 0, 0)
#define LDK 72
#define LDK2 136

// fragment read from LDS tile stored [row][k], row stride LDK (bf16):
// lane l reads 8 contiguous k at row (l&15), k-offset (l>>4)*8
__device__ __forceinline__ bf16x8 ldsfrag(const bf16* p) {
  const int lane = threadIdx.x & 63;
  return *(const bf16x8*)(p + (lane & 15) * LDK + (lane >> 4) * 8);
}
// same for stride-136 tiles (BK=128); 68 words % 32 = 4 -> same bank pattern
__device__ __forceinline__ bf16x8 ldsfrag2(const bf16* p) {
  const int lane = threadIdx.x & 63;
  return *(const bf16x8*)(p + (lane & 15) * LDK2 + (lane >> 4) * 8);
}

__device__ __forceinline__ bf16x8 cvt8(float4 a, float4 b) {
  return (bf16x8){(bf16)a.x, (bf16)a.y, (bf16)a.z, (bf16)a.w,
                  (bf16)b.x, (bf16)b.y, (bf16)b.z, (bf16)b.w};
}

// ---------------------------------------------------------------------------
// convert phi_w (131072 f) and out_w (1048576 f) to bf16
// ---------------------------------------------------------------------------
__global__ void k_convert(const float* __restrict__ phi, const float* __restrict__ ow,
                          bf16* __restrict__ phi_bf, bf16* __restrict__ ow_bf)
{
  if (blockIdx.x < 128) {
    int i = blockIdx.x * 256 + threadIdx.x;
    float4 v = ((const float4*)phi)[i];
    ((bf16x4*)phi_bf)[i] = (bf16x4){(bf16)v.x, (bf16)v.y, (bf16)v.z, (bf16)v.w};
  } else {
    int i = (blockIdx.x - 128) * 256 + threadIdx.x;
    float4 v = ((const float4*)ow)[i];
    ((bf16x4*)ow_bf)[i] = (bf16x4){(bf16)v.x, (bf16)v.y, (bf16)v.z, (bf16)v.w};
  }
}

// ---------------------------------------------------------------------------
// logits = x @ phi_bf^T (M=32768, N=128, K=1024). BM=32, BN=128, BK=64,
// 1024 blocks (4/CU for latency hiding), 4 waves (wave tile 32x32).
// Emits Xbf, fp32 logits, CW (combine softmax), per-32-row dispatch partials.
// ---------------------------------------------------------------------------
__global__ __launch_bounds__(256) void k_logits(
    const float* __restrict__ X, const bf16* __restrict__ Phi,
    float* __restrict__ L, bf16* __restrict__ Xbf, bf16* __restrict__ CW,
    float* __restrict__ redM, float* __restrict__ redS)
{
  __shared__ __align__(16) char smraw[23040];   // As(4608)+Bs(18432); S=17024
  bf16 (*As)[LDK] = (bf16(*)[LDK])smraw;
  bf16 (*Bs)[LDK] = (bf16(*)[LDK])(smraw + 32 * LDK * 2);
  float (*S)[133] = (float(*)[133])smraw;

  const int m0 = blockIdx.x * 32;
  const int tid = threadIdx.x;
  const int wave = tid >> 6, lane = tid & 63;
  const int wn = wave * 32;

  f32x4 acc[2][2];
#pragma unroll
  for (int i = 0; i < 2; ++i)
#pragma unroll
    for (int j = 0; j < 2; ++j) acc[i][j] = (f32x4){0.f, 0.f, 0.f, 0.f};

  const int ar = tid >> 3, ac = (tid & 7) * 8;   // 32 rows x 64k (x)
  const int br = tid >> 1, bc = (tid & 1) * 32;  // 128 rows x 64k (phi)

  for (int k0 = 0; k0 < 1024; k0 += 64) {
    const float* xp = X + (long)(m0 + ar) * 1024 + k0 + ac;
    float4 v0 = *(const float4*)(xp + 0);
    float4 v1 = *(const float4*)(xp + 4);
    bf16x8 p0 = cvt8(v0, v1);
    *(bf16x8*)&As[ar][ac] = p0;
    *(bf16x8*)(Xbf + (long)(m0 + ar) * 1024 + k0 + ac) = p0;

    const bf16* pp = Phi + (long)br * 1024 + k0 + bc;
    *(bf16x8*)&Bs[br][bc + 0]  = *(const bf16x8*)(pp + 0);
    *(bf16x8*)&Bs[br][bc + 8]  = *(const bf16x8*)(pp + 8);
    *(bf16x8*)&Bs[br][bc + 16] = *(const bf16x8*)(pp + 16);
    *(bf16x8*)&Bs[br][bc + 24] = *(const bf16x8*)(pp + 24);
    __syncthreads();
#pragma unroll
    for (int kk = 0; kk < 64; kk += 32) {
      bf16x8 a0 = ldsfrag(&As[0][kk]);
      bf16x8 a1 = ldsfrag(&As[16][kk]);
      bf16x8 b0 = ldsfrag(&Bs[wn][kk]);
      bf16x8 b1 = ldsfrag(&Bs[wn + 16][kk]);
      acc[0][0] = MFMA16(a0, b0, acc[0][0]);
      acc[0][1] = MFMA16(a0, b1, acc[0][1]);
      acc[1][0] = MFMA16(a1, b0, acc[1][0]);
      acc[1][1] = MFMA16(a1, b1, acc[1][1]);
    }
    __syncthreads();
  }
  const int cc = lane & 15, rr = (lane >> 4) * 4;
#pragma unroll
  for (int m = 0; m < 2; ++m)
#pragma unroll
    for (int n = 0; n < 2; ++n)
#pragma unroll
      for (int j = 0; j < 4; ++j) {
        const int row = m * 16 + rr + j, col = wn + n * 16 + cc;
        const float val = acc[m][n][j];
        L[(long)(m0 + row) * 128 + col] = val;
        S[row][col] = val;
      }
  __syncthreads();

  // --- combine softmax (rows complete: T=128 = tile width) -> CW ---
  const int r = tid >> 3, q = tid & 7;   // 32 rows x 8 lanes (16 vals each)
  float v[16];
#pragma unroll
  for (int i = 0; i < 4; ++i)
#pragma unroll
    for (int j = 0; j < 4; ++j) v[i * 4 + j] = S[r][q * 4 + i * 32 + j];
  float mx = -1e30f;
#pragma unroll
  for (int i = 0; i < 16; ++i) mx = fmaxf(mx, v[i]);
  mx = fmaxf(mx, __shfl_xor(mx, 1));
  mx = fmaxf(mx, __shfl_xor(mx, 2));
  mx = fmaxf(mx, __shfl_xor(mx, 4));
  float sum = 0.f;
#pragma unroll
  for (int i = 0; i < 16; ++i) { v[i] = expf(v[i] - mx); sum += v[i]; }
  sum += __shfl_xor(sum, 1);
  sum += __shfl_xor(sum, 2);
  sum += __shfl_xor(sum, 4);
  const float inv = 1.f / sum;
  bf16* cwr = CW + (long)(m0 + r) * 128 + q * 4;
#pragma unroll
  for (int i = 0; i < 4; ++i)
    *(bf16x4*)(cwr + i * 32) = (bf16x4){(bf16)(v[i*4+0]*inv), (bf16)(v[i*4+1]*inv),
                                        (bf16)(v[i*4+2]*inv), (bf16)(v[i*4+3]*inv)};

  // --- dispatch partial stats over this block's 32 rows, per t ---
  if (tid < 128) {
    const int t = tid;
    float m = -1e30f, s = 0.f;
    for (int rj = 0; rj < 32; ++rj) {
      float val = S[rj][t];
      if (val > m) { s = s * expf(m - val) + 1.f; m = val; }
      else         { s += expf(val - m); }
    }
    redM[(long)blockIdx.x * 128 + t] = m;
    redS[(long)blockIdx.x * 128 + t] = s;
  }
}

// ---------------------------------------------------------------------------
// dispatch softmax final stats: reduce 128 chunks per b
// ---------------------------------------------------------------------------
__global__ void disp_final(const float* __restrict__ redM, const float* __restrict__ redS,
                           float* __restrict__ Mf, float* __restrict__ Zf)
{
  int idx = blockIdx.x * 256 + threadIdx.x;   // 1024 total
  int b = idx >> 7, t = idx & 127;
  float m = -1e30f, s = 0.f;
  for (int c = 0; c < 128; ++c) {
    float mc = redM[((long)b * 128 + c) * 128 + t];
    float sc = redS[((long)b * 128 + c) * 128 + t];
    float nm = fmaxf(m, mc);
    s = s * expf(m - nm) + sc * expf(mc - nm);
    m = nm;
  }
  Mf[idx] = m;
  Zf[idx] = 1.f / s;
}

// ---------------------------------------------------------------------------
// dispatch weights, TRANSPOSED + bf16: DWT[b][t][n] = softmax_n(logits)[n][t]
// ---------------------------------------------------------------------------
__global__ __launch_bounds__(256) void k_dwt(const float* __restrict__ L,
    const float* __restrict__ Mf, const float* __restrict__ Zf, bf16* __restrict__ DWT)
{
  __shared__ float S[64][132];
  const int b = blockIdx.y, n0 = blockIdx.x * 64;
  const int tid = threadIdx.x;
  const int r = tid >> 2;            // n-row 0..63
  const int c0 = (tid & 3) * 32;     // t col base
  const float* Lp = L + ((long)b * N_ + n0 + r) * T_ + c0;
#pragma unroll
  for (int i = 0; i < 32; i += 4) {
    float4 v = *(const float4*)(Lp + i);
    S[r][c0 + i + 0] = v.x;
    S[r][c0 + i + 1] = v.y;
    S[r][c0 + i + 2] = v.z;
    S[r][c0 + i + 3] = v.w;
  }
  __syncthreads();
  const int nc = (tid & 7) * 8;
  for (int ti = tid >> 3; ti < 128; ti += 32) {
    const float mf = Mf[b * 128 + ti], zf = Zf[b * 128 + ti];
    bf16x8 o;
#pragma unroll
    for (int j = 0; j < 8; ++j) o[j] = (bf16)(expf(S[nc + j][ti] - mf) * zf);
    *(bf16x8*)(DWT + ((long)b * 128 + ti) * 4096 + n0 + nc) = o;
  }
}

// ---------------------------------------------------------------------------
// slots (r9-proven): BK=64, grid x=(b,chunk), y=d0 (XCD-shared DWT panels),
// XOR-swizzled transposed B staging, bf16 Part.
// ---------------------------------------------------------------------------
__device__ __forceinline__ bf16x8 ldsfragB(const bf16 (*Bs)[LDK], int dbase, int kk) {
  const int l = threadIdx.x & 63;
  const int d = dbase + (l & 15);
  const int c = ((l >> 4) * 8 + kk) ^ (((d >> 5) & 3) << 4);
  return *(const bf16x8*)(&Bs[d][c]);
}

__global__ __launch_bounds__(256) void k_slots(
    const bf16* __restrict__ DWT, const bf16* __restrict__ Xbf, bf16* __restrict__ Part)
{
  __shared__ bf16 As[128][LDK];    // [t][n]
  __shared__ bf16 Bs[128][LDK];    // [d][n ^ ((d>>5)<<4)]
  const int bz = blockIdx.x;       // 0..63
  const int b = bz >> 3, chunk = bz & 7;
  const int d0 = blockIdx.y * 128;
  const int tid = threadIdx.x, wave = tid >> 6, lane = tid & 63;
  const int wm = (wave >> 1) * 64, wn = (wave & 1) * 64;

  f32x4 acc[4][4];
#pragma unroll
  for (int i = 0; i < 4; ++i)
#pragma unroll
    for (int j = 0; j < 4; ++j) acc[i][j] = (f32x4){0.f, 0.f, 0.f, 0.f};

  const int at = tid >> 1, anc = (tid & 1) * 32;
  const int bn = tid >> 2, bq = tid & 3, bdc = bq * 32;
  const int bcol = bn ^ (bq << 4);
  const long dwt_b = (long)b * 128 * 4096;
  const long x_b   = (long)b * 4096 * 1024;

  for (int k0 = 0; k0 < 512; k0 += 64) {
    const int nbase = chunk * 512 + k0;
    const bf16* ap = DWT + dwt_b + (long)at * 4096 + nbase + anc;
    *(bf16x8*)&As[at][anc + 0]  = *(const bf16x8*)(ap + 0);
    *(bf16x8*)&As[at][anc + 8]  = *(const bf16x8*)(ap + 8);
    *(bf16x8*)&As[at][anc + 16] = *(const bf16x8*)(ap + 16);
    *(bf16x8*)&As[at][anc + 24] = *(const bf16x8*)(ap + 24);
    const bf16* xp = Xbf + x_b + (long)(nbase + bn) * 1024 + d0 + bdc;
    bf16x8 q0 = *(const bf16x8*)(xp + 0);
    bf16x8 q1 = *(const bf16x8*)(xp + 8);
    bf16x8 q2 = *(const bf16x8*)(xp + 16);
    bf16x8 q3 = *(const bf16x8*)(xp + 24);
#pragma unroll
    for (int i = 0; i < 8; ++i) {
      Bs[bdc + i][bcol]      = q0[i];
      Bs[bdc + 8 + i][bcol]  = q1[i];
      Bs[bdc + 16 + i][bcol] = q2[i];
      Bs[bdc + 24 + i][bcol] = q3[i];
    }
    __syncthreads();
#pragma unroll
    for (int kk = 0; kk < 64; kk += 32) {
      bf16x8 af[4], bfr[4];
#pragma unroll
      for (int m = 0; m < 4; ++m) af[m]  = ldsfrag(&As[wm + m * 16][kk]);
#pragma unroll
      for (int n = 0; n < 4; ++n) bfr[n] = ldsfragB(Bs, wn + n * 16, kk);
#pragma unroll
      for (int m = 0; m < 4; ++m)
#pragma unroll
        for (int n = 0; n < 4; ++n)
          acc[m][n] = MFMA16(af[m], bfr[n], acc[m][n]);
    }
    __syncthreads();
  }
  const int cc = lane & 15, rr = (lane >> 4) * 4;
  bf16* Cp = Part + ((long)chunk * 8 + b) * 128 * 1024;
#pragma unroll
  for (int m = 0; m < 4; ++m)
#pragma unroll
    for (int n = 0; n < 4; ++n)
#pragma unroll
      for (int j = 0; j < 4; ++j)
        Cp[(long)(wm + m * 16 + rr + j) * 1024 + d0 + wn + n * 16 + cc] =
            (bf16)acc[m][n][j];
}

__global__ void k_reduce8(const bf16* __restrict__ P, bf16* __restrict__ O)
{
  long base = ((long)blockIdx.x * 256 + threadIdx.x) * 8;
  f32x4 slo = (f32x4){0.f,0.f,0.f,0.f}, shi = (f32x4){0.f,0.f,0.f,0.f};
#pragma unroll
  for (int c = 0; c < 8; ++c) {
    bf16x8 v = *(const bf16x8*)(P + (long)c * 1048576 + base);
#pragma unroll
    for (int j = 0; j < 4; ++j) { slo[j] += (float)v[j]; shi[j] += (float)v[4 + j]; }
  }
  bf16x8 o;
#pragma unroll
  for (int j = 0; j < 4; ++j) { o[j] = (bf16)slo[j]; o[4 + j] = (bf16)shi[j]; }
  *(bf16x8*)(O + base) = o;
}

// ---------------------------------------------------------------------------
// per-expert MLP layer: M=16 rows, N=1024(h) tiled 64, K=1024; weights fp32.
// BK=128 (proven r9). INL=0: A rows at (b*128+e*2+s); INL=1: compact.
// ---------------------------------------------------------------------------
template<int GELU, int INL>
__global__ __launch_bounds__(256) void k_expert(
    const bf16* __restrict__ Ab, const float* __restrict__ W,
    const float* __restrict__ bias, bf16* __restrict__ Out)
{
  __shared__ bf16 As[16][LDK2];
  __shared__ bf16 Bs[64][LDK2];
  const int e = blockIdx.y;
  const int h0 = blockIdx.x * 64;
  const int tid = threadIdx.x, wave = tid >> 6, lane = tid & 63;
  f32x4 acc = (f32x4){0.f, 0.f, 0.f, 0.f};

  const int hr = tid >> 2, kc = (tid & 3) * 32;
  const int ar = tid >> 4, akc = (tid & 15) * 8;
  const long arow = (INL == 0) ? (long)((ar >> 1) * 128 + e * 2 + (ar & 1))
                               : (long)(e * 16 + ar);

  for (int k0 = 0; k0 < 1024; k0 += 128) {
    *(bf16x8*)&As[ar][akc] = *(const bf16x8*)(Ab + arow * 1024 + k0 + akc);
    const float* wp = W + ((long)e * 1024 + h0 + hr) * 1024 + k0 + kc;
    float4 w0 = *(const float4*)(wp + 0);
    float4 w1 = *(const float4*)(wp + 4);
    float4 w2 = *(const float4*)(wp + 8);
    float4 w3 = *(const float4*)(wp + 12);
    float4 w4 = *(const float4*)(wp + 16);
    float4 w5 = *(const float4*)(wp + 20);
    float4 w6 = *(const float4*)(wp + 24);
    float4 w7 = *(const float4*)(wp + 28);
    *(bf16x8*)&Bs[hr][kc]      = cvt8(w0, w1);
    *(bf16x8*)&Bs[hr][kc + 8]  = cvt8(w2, w3);
    *(bf16x8*)&Bs[hr][kc + 16] = cvt8(w4, w5);
    *(bf16x8*)&Bs[hr][kc + 24] = cvt8(w6, w7);
    __syncthreads();
#pragma unroll
    for (int kk = 0; kk < 128; kk += 32) {
      bf16x8 a0 = ldsfrag2(&As[0][kk]);
      bf16x8 b0 = ldsfrag2(&Bs[wave * 16][kk]);
      acc = MFMA16(a0, b0, acc);
    }
    __syncthreads();
  }
  const int cc = lane & 15, rr = (lane >> 4) * 4;
  const int h = h0 + wave * 16 + cc;
  const float bs = bias[e * 1024 + h];
#pragma unroll
  for (int j = 0; j < 4; ++j) {
    float v = acc[j] + bs;
    if (GELU) {
      float x3 = v * v * v;
      v = 0.5f * v * (1.f + tanhf(0.7978845608028654f * (v + 0.044715f * x3)));
    }
    int m = rr + j;
    long orow = (INL == 0) ? (long)(e * 16 + m) : (long)((m >> 1) * 128 + e * 2 + (m & 1));
    Out[orow * 1024 + h] = (bf16)v;
  }
}

// ---------------------------------------------------------------------------
// projT[o][bt] = sum_d out_w_bf[o][d] * outs_bf[bt][d]   (1024x1024x1024)
// BM=BN=64, 4 waves (32x32 each)
// ---------------------------------------------------------------------------
__global__ __launch_bounds__(256) void k_proj(
    const bf16* __restrict__ OWbf, const bf16* __restrict__ OS, bf16* __restrict__ PT)
{
  __shared__ bf16 As[64][LDK];
  __shared__ bf16 Bs[64][LDK];
  const int o0 = blockIdx.y * 64, t0 = blockIdx.x * 64;
  const int tid = threadIdx.x, wave = tid >> 6, lane = tid & 63;
  const int wm = (wave >> 1) * 32, wn = (wave & 1) * 32;
  f32x4 acc[2][2];
#pragma unroll
  for (int i = 0; i < 2; ++i)
#pragma unroll
    for (int j = 0; j < 2; ++j) acc[i][j] = (f32x4){0.f, 0.f, 0.f, 0.f};

  const int r = tid >> 2, kc = (tid & 3) * 16;
  for (int k0 = 0; k0 < 1024; k0 += 64) {
    const bf16* apo = OWbf + (long)(o0 + r) * 1024 + k0 + kc;
    *(bf16x8*)&As[r][kc]     = *(const bf16x8*)(apo + 0);
    *(bf16x8*)&As[r][kc + 8] = *(const bf16x8*)(apo + 8);
    const bf16* bpo = OS + (long)(t0 + r) * 1024 + k0 + kc;
    *(bf16x8*)&Bs[r][kc]     = *(const bf16x8*)(bpo + 0);
    *(bf16x8*)&Bs[r][kc + 8] = *(const bf16x8*)(bpo + 8);
    __syncthreads();
#pragma unroll
    for (int kk = 0; kk < 64; kk += 32) {
      bf16x8 a0 = ldsfrag(&As[wm][kk]);
      bf16x8 a1 = ldsfrag(&As[wm + 16][kk]);
      bf16x8 b0 = ldsfrag(&Bs[wn][kk]);
      bf16x8 b1 = ldsfrag(&Bs[wn + 16][kk]);
      acc[0][0] = MFMA16(a0, b0, acc[0][0]);
      acc[0][1] = MFMA16(a0, b1, acc[0][1]);
      acc[1][0] = MFMA16(a1, b0, acc[1][0]);
      acc[1][1] = MFMA16(a1, b1, acc[1][1]);
    }
    __syncthreads();
  }
  const int cc = lane & 15, rr = (lane >> 4) * 4;
#pragma unroll
  for (int m = 0; m < 2; ++m)
#pragma unroll
    for (int n = 0; n < 2; ++n)
#pragma unroll
      for (int j = 0; j < 4; ++j)
        PT[(long)(o0 + wm + m * 16 + rr + j) * 1024 + t0 + wn + n * 16 + cc] =
            (bf16)acc[m][n][j];
}

// ---------------------------------------------------------------------------
// out[b][n][o] = sum_t CW[b][n][t] * PT[o][b*128+t] + out_b[o]; also aux=0.
// per b: M=4096, N=1024, K=128; BM=128, BN=128, BK=64.
// GRID: x=m0 (32), y=o0 (8), z=b — blocks sharing a CW A-tile (varying o0)
// are stride-32 apart => same XCD => CW tile L2-shared (r12-proven).
// ---------------------------------------------------------------------------
__global__ __launch_bounds__(256) void k_combine(
    const bf16* __restrict__ CW, const bf16* __restrict__ PT,
    const float* __restrict__ ob, float* __restrict__ O)
{
  __shared__ bf16 As[128][LDK];
  __shared__ bf16 Bs[128][LDK];
  const int b = blockIdx.z, m0 = blockIdx.x * 128, o0 = blockIdx.y * 128;
  const int tid = threadIdx.x, wave = tid >> 6, lane = tid & 63;
  const int wm = (wave >> 1) * 64, wn = (wave & 1) * 64;

  if (blockIdx.x == 0 && blockIdx.y == 0 && blockIdx.z == 0 && tid == 0)
    O[(long)B_ * N_ * D_] = 0.f;   // aux loss scalar

  f32x4 acc[4][4];
#pragma unroll
  for (int i = 0; i < 4; ++i)
#pragma unroll
    for (int j = 0; j < 4; ++j) acc[i][j] = (f32x4){0.f, 0.f, 0.f, 0.f};

  const int r = tid >> 1, tc = (tid & 1) * 32;
  for (int k0 = 0; k0 < 128; k0 += 64) {
    const bf16* ap = CW + ((long)b * N_ + m0 + r) * 128 + k0 + tc;
    *(bf16x8*)&As[r][tc + 0]  = *(const bf16x8*)(ap + 0);
    *(bf16x8*)&As[r][tc + 8]  = *(const bf16x8*)(ap + 8);
    *(bf16x8*)&As[r][tc + 16] = *(const bf16x8*)(ap + 16);
    *(bf16x8*)&As[r][tc + 24] = *(const bf16x8*)(ap + 24);
    const bf16* bp = PT + (long)(o0 + r) * 1024 + b * 128 + k0 + tc;
    *(bf16x8*)&Bs[r][tc + 0]  = *(const bf16x8*)(bp + 0);
    *(bf16x8*)&Bs[r][tc + 8]  = *(const bf16x8*)(bp + 8);
    *(bf16x8*)&Bs[r][tc + 16] = *(const bf16x8*)(bp + 16);
    *(bf16x8*)&Bs[r][tc + 24] = *(const bf16x8*)(bp + 24);
    __syncthreads();
#pragma unroll
    for (int kk = 0; kk < 64; kk += 32) {
      bf16x8 af[4], bfr[4];
#pragma unroll
      for (int m = 0; m < 4; ++m) af[m]  = ldsfrag(&As[wm + m * 16][kk]);
#pragma unroll
      for (int n = 0; n < 4; ++n) bfr[n] = ldsfrag(&Bs[wn + n * 16][kk]);
#pragma unroll
      for (int m = 0; m < 4; ++m)
#pragma unroll
        for (int n = 0; n < 4; ++n)
          acc[m][n] = MFMA16(af[m], bfr[n], acc[m][n]);
    }
    __syncthreads();
  }
  const int cc = lane & 15, rr = (lane >> 4) * 4;
#pragma unroll
  for (int n = 0; n < 4; ++n) {
    const int o = o0 + wn + n * 16 + cc;
    const float bv = ob[o];
#pragma unroll
    for (int m = 0; m < 4; ++m)
#pragma unroll
      for (int j = 0; j < 4; ++j)
        O[((long)b * N_ + m0 + wm + m * 16 + rr + j) * 1024 + o] = acc[m][n][j] + bv;
  }
}

// ---------------------------------------------------------------------------
extern "C" void kernel_launch(void* const* d_in, const int* in_sizes, int n_in,
                              void* d_out, int out_size, void* d_ws, size_t ws_size,
                              hipStream_t stream)
{
  const float* x     = (const float*)d_in[0];
  const float* phi_w = (const float*)d_in[1];
  const float* fc1_w = (const float*)d_in[2];
  const float* fc1_b = (const float*)d_in[3];
  const float* fc2_w = (const float*)d_in[4];
  const float* fc2_b = (const float*)d_in[5];
  const float* out_w = (const float*)d_in[6];
  const float* out_b = (const float*)d_in[7];
  float* out = (float*)d_out;

  float* ws     = (float*)d_ws;
  float* logits = ws;                         // 4,194,304 f
  float* redM   = logits + 4194304;           // 131,072 (1024 chunks x 128)
  float* redS   = redM + 131072;              // 131,072
  float* Mf     = redS + 131072;              // 1,024
  float* Zf     = Mf + 1024;                  // 1,024
  bf16* DWT     = (bf16*)(Zf + 1024);         // 4,194,304 bf16
  bf16* CW      = DWT + 4194304;              // 4,194,304 bf16
  bf16* slots   = CW + 4194304;               // 1,048,576 bf16
  bf16* hbuf    = slots + 1048576;            // 1,048,576 bf16
  bf16* outs    = hbuf + 1048576;             // 1,048,576 bf16
  bf16* projT   = outs + 1048576;             // 1,048,576 bf16
  bf16* phi_bf  = projT + 1048576;            // 131,072 bf16
  bf16* outw_bf = phi_bf + 131072;            // 1,048,576 bf16

  // scratch in d_out (dead until k_combine writes it):
  bf16* Xbf   = (bf16*)d_out;                 // 33,554,432 bf16 = 64 MB
  bf16* Part  = Xbf + 33554432;               // 8 x 1,048,576 bf16 = 16 MB

  k_convert<<<dim3(1152), 256, 0, stream>>>(phi_w, out_w, phi_bf, outw_bf);
  k_logits<<<dim3(1024), 256, 0, stream>>>(x, phi_bf, logits, Xbf, CW, redM, redS);
  disp_final<<<dim3(4), 256, 0, stream>>>(redM, redS, Mf, Zf);
  k_dwt<<<dim3(64, 8), 256, 0, stream>>>(logits, Mf, Zf, DWT);
  k_slots<<<dim3(64, 8), 256, 0, stream>>>(DWT, Xbf, Part);
  k_reduce8<<<dim3(512), 256, 0, stream>>>(Part, slots);
  k_expert<1, 0><<<dim3(16, 64), 256, 0, stream>>>(slots, fc1_w, fc1_b, hbuf);
  k_expert<0, 1><<<dim3(16, 64), 256, 0, stream>>>(hbuf, fc2_w, fc2_b, outs);
  k_proj<<<dim3(16, 16), 256, 0, stream>>>(outw_bf, outs, projT);
  k_combine<<<dim3(32, 8, 8), 256, 0, stream>>>(CW, projT, out_b, out);
}

// Round 14
// 286.872 us; speedup vs baseline: 1.0128x; 1.0128x over previous
//
#include <hip/hip_runtime.h>
#include <math.h>

#define B_ 8
#define N_ 4096
#define D_ 1024
#define E_ 64
#define T_ 128

using bf16   = __bf16;
using bf16x4 = __attribute__((ext_vector_type(4))) __bf16;
using bf16x8 = __attribute__((ext_vector_type(8))) __bf16;
using f32x4  = __attribute__((ext_vector_type(4))) float;

#define MFMA16(a, b, c) __builtin_amdgcn_mfma_f32_16x16x32_bf16(a, b, c, 0, 0, 0)
#define LDK 72
#define LDK2 136

// fragment read from LDS tile stored [row][k], row stride LDK (bf16):
// lane l reads 8 contiguous k at row (l&15), k-offset (l>>4)*8
__device__ __forceinline__ bf16x8 ldsfrag(const bf16* p) {
  const int lane = threadIdx.x & 63;
  return *(const bf16x8*)(p + (lane & 15) * LDK + (lane >> 4) * 8);
}
// same for stride-136 tiles (BK=128); 68 words % 32 = 4 -> same bank pattern
__device__ __forceinline__ bf16x8 ldsfrag2(const bf16* p) {
  const int lane = threadIdx.x & 63;
  return *(const bf16x8*)(p + (lane & 15) * LDK2 + (lane >> 4) * 8);
}

__device__ __forceinline__ bf16x8 cvt8(float4 a, float4 b) {
  return (bf16x8){(bf16)a.x, (bf16)a.y, (bf16)a.z, (bf16)a.w,
                  (bf16)b.x, (bf16)b.y, (bf16)b.z, (bf16)b.w};
}

// ---------------------------------------------------------------------------
// convert phi_w (131072 f) and out_w (1048576 f) to bf16
// ---------------------------------------------------------------------------
__global__ void k_convert(const float* __restrict__ phi, const float* __restrict__ ow,
                          bf16* __restrict__ phi_bf, bf16* __restrict__ ow_bf)
{
  if (blockIdx.x < 128) {
    int i = blockIdx.x * 256 + threadIdx.x;
    float4 v = ((const float4*)phi)[i];
    ((bf16x4*)phi_bf)[i] = (bf16x4){(bf16)v.x, (bf16)v.y, (bf16)v.z, (bf16)v.w};
  } else {
    int i = (blockIdx.x - 128) * 256 + threadIdx.x;
    float4 v = ((const float4*)ow)[i];
    ((bf16x4*)ow_bf)[i] = (bf16x4){(bf16)v.x, (bf16)v.y, (bf16)v.z, (bf16)v.w};
  }
}

// ---------------------------------------------------------------------------
// logits = x @ phi_bf^T  (M=32768, N=128, K=1024), BK=64; emits Xbf, logits,
// CW (combine softmax), per-64-row dispatch partials. (r9-proven form)
// ---------------------------------------------------------------------------
__global__ __launch_bounds__(256) void k_logits(
    const float* __restrict__ X, const bf16* __restrict__ Phi,
    float* __restrict__ L, bf16* __restrict__ Xbf, bf16* __restrict__ CW,
    float* __restrict__ redM, float* __restrict__ redS)
{
  __shared__ __align__(16) char smraw[34048];   // max(As+Bs=27648, S=34048)
  bf16 (*As)[LDK] = (bf16(*)[LDK])smraw;
  bf16 (*Bs)[LDK] = (bf16(*)[LDK])(smraw + 64 * LDK * 2);
  float (*S)[133] = (float(*)[133])smraw;

  const int m0 = blockIdx.x * 64;
  const int tid = threadIdx.x;
  const int wave = tid >> 6, lane = tid & 63;
  const int wm = (wave >> 1) * 32;
  const int wn = (wave & 1) * 64;

  f32x4 acc[2][4];
#pragma unroll
  for (int i = 0; i < 2; ++i)
#pragma unroll
    for (int j = 0; j < 4; ++j) acc[i][j] = (f32x4){0.f, 0.f, 0.f, 0.f};

  const int ar = tid >> 2, ac = (tid & 3) * 16;
  const int br = tid >> 1, bc = (tid & 1) * 32;

  for (int k0 = 0; k0 < 1024; k0 += 64) {
    const float* xp = X + (long)(m0 + ar) * 1024 + k0 + ac;
    float4 v0 = *(const float4*)(xp + 0);
    float4 v1 = *(const float4*)(xp + 4);
    float4 v2 = *(const float4*)(xp + 8);
    float4 v3 = *(const float4*)(xp + 12);
    bf16x8 p0 = cvt8(v0, v1);
    bf16x8 p1 = cvt8(v2, v3);
    *(bf16x8*)&As[ar][ac]     = p0;
    *(bf16x8*)&As[ar][ac + 8] = p1;
    bf16* xo = Xbf + (long)(m0 + ar) * 1024 + k0 + ac;
    *(bf16x8*)xo       = p0;
    *(bf16x8*)(xo + 8) = p1;

    const bf16* pp = Phi + (long)br * 1024 + k0 + bc;
    *(bf16x8*)&Bs[br][bc + 0]  = *(const bf16x8*)(pp + 0);
    *(bf16x8*)&Bs[br][bc + 8]  = *(const bf16x8*)(pp + 8);
    *(bf16x8*)&Bs[br][bc + 16] = *(const bf16x8*)(pp + 16);
    *(bf16x8*)&Bs[br][bc + 24] = *(const bf16x8*)(pp + 24);
    __syncthreads();
#pragma unroll
    for (int kk = 0; kk < 64; kk += 32) {
      bf16x8 a0 = ldsfrag(&As[wm][kk]);
      bf16x8 a1 = ldsfrag(&As[wm + 16][kk]);
#pragma unroll
      for (int n = 0; n < 4; ++n) {
        bf16x8 bb = ldsfrag(&Bs[wn + n * 16][kk]);
        acc[0][n] = MFMA16(a0, bb, acc[0][n]);
        acc[1][n] = MFMA16(a1, bb, acc[1][n]);
      }
    }
    __syncthreads();
  }
  const int cc = lane & 15, rr = (lane >> 4) * 4;
#pragma unroll
  for (int m = 0; m < 2; ++m)
#pragma unroll
    for (int n = 0; n < 4; ++n)
#pragma unroll
      for (int j = 0; j < 4; ++j) {
        const float val = acc[m][n][j];
        L[(long)(m0 + wm + m * 16 + rr + j) * 128 + wn + n * 16 + cc] = val;
        S[wm + m * 16 + rr + j][wn + n * 16 + cc] = val;
      }
  __syncthreads();

  // --- combine softmax (rows complete: T=128 = tile width) -> CW ---
  const int r = tid >> 2, q = tid & 3;
  float v[32];
#pragma unroll
  for (int i = 0; i < 8; ++i)
#pragma unroll
    for (int j = 0; j < 4; ++j) v[i * 4 + j] = S[r][q * 4 + i * 16 + j];
  float mx = -1e30f;
#pragma unroll
  for (int i = 0; i < 32; ++i) mx = fmaxf(mx, v[i]);
  mx = fmaxf(mx, __shfl_xor(mx, 1));
  mx = fmaxf(mx, __shfl_xor(mx, 2));
  float sum = 0.f;
#pragma unroll
  for (int i = 0; i < 32; ++i) { v[i] = expf(v[i] - mx); sum += v[i]; }
  sum += __shfl_xor(sum, 1);
  sum += __shfl_xor(sum, 2);
  const float inv = 1.f / sum;
  bf16* cwr = CW + (long)(m0 + r) * 128 + q * 4;
#pragma unroll
  for (int i = 0; i < 8; ++i)
    *(bf16x4*)(cwr + i * 16) = (bf16x4){(bf16)(v[i*4+0]*inv), (bf16)(v[i*4+1]*inv),
                                        (bf16)(v[i*4+2]*inv), (bf16)(v[i*4+3]*inv)};

  // --- dispatch partial stats over this block's 64 rows, per t ---
  if (tid < 128) {
    const int t = tid;
    float m = -1e30f, s = 0.f;
    for (int rj = 0; rj < 64; ++rj) {
      float val = S[rj][t];
      if (val > m) { s = s * expf(m - val) + 1.f; m = val; }
      else         { s += expf(val - m); }
    }
    const long chunk = m0 >> 6;      // 0..511 (= b*64 + within-b chunk)
    redM[chunk * 128 + t] = m;
    redS[chunk * 128 + t] = s;
  }
}

// ---------------------------------------------------------------------------
// dispatch softmax final stats: reduce 64 chunks per b
// ---------------------------------------------------------------------------
__global__ void disp_final(const float* __restrict__ redM, const float* __restrict__ redS,
                           float* __restrict__ Mf, float* __restrict__ Zf)
{
  int idx = blockIdx.x * 256 + threadIdx.x;   // 1024 total
  int b = idx >> 7, t = idx & 127;
  float m = -1e30f, s = 0.f;
  for (int c = 0; c < 64; ++c) {
    float mc = redM[((long)b * 64 + c) * 128 + t];
    float sc = redS[((long)b * 64 + c) * 128 + t];
    float nm = fmaxf(m, mc);
    s = s * expf(m - nm) + sc * expf(mc - nm);
    m = nm;
  }
  Mf[idx] = m;
  Zf[idx] = 1.f / s;
}

// ---------------------------------------------------------------------------
// dispatch weights, TRANSPOSED + bf16: DWT[b][t][n] = softmax_n(logits)[n][t]
// ---------------------------------------------------------------------------
__global__ __launch_bounds__(256) void k_dwt(const float* __restrict__ L,
    const float* __restrict__ Mf, const float* __restrict__ Zf, bf16* __restrict__ DWT)
{
  __shared__ float S[64][132];
  const int b = blockIdx.y, n0 = blockIdx.x * 64;
  const int tid = threadIdx.x;
  const int r = tid >> 2;            // n-row 0..63
  const int c0 = (tid & 3) * 32;     // t col base
  const float* Lp = L + ((long)b * N_ + n0 + r) * T_ + c0;
#pragma unroll
  for (int i = 0; i < 32; i += 4) {
    float4 v = *(const float4*)(Lp + i);
    S[r][c0 + i + 0] = v.x;
    S[r][c0 + i + 1] = v.y;
    S[r][c0 + i + 2] = v.z;
    S[r][c0 + i + 3] = v.w;
  }
  __syncthreads();
  const int nc = (tid & 7) * 8;
  for (int ti = tid >> 3; ti < 128; ti += 32) {
    const float mf = Mf[b * 128 + ti], zf = Zf[b * 128 + ti];
    bf16x8 o;
#pragma unroll
    for (int j = 0; j < 8; ++j) o[j] = (bf16)(expf(S[nc + j][ti] - mf) * zf);
    *(bf16x8*)(DWT + ((long)b * 128 + ti) * 4096 + n0 + nc) = o;
  }
}

// ---------------------------------------------------------------------------
// slots (r9-proven): BK=64, grid x=(b,chunk), y=d0 (XCD-shared DWT panels),
// XOR-swizzled transposed B staging, bf16 Part.
// ---------------------------------------------------------------------------
__device__ __forceinline__ bf16x8 ldsfragB(const bf16 (*Bs)[LDK], int dbase, int kk) {
  const int l = threadIdx.x & 63;
  const int d = dbase + (l & 15);
  const int c = ((l >> 4) * 8 + kk) ^ (((d >> 5) & 3) << 4);
  return *(const bf16x8*)(&Bs[d][c]);
}

__global__ __launch_bounds__(256) void k_slots(
    const bf16* __restrict__ DWT, const bf16* __restrict__ Xbf, bf16* __restrict__ Part)
{
  __shared__ bf16 As[128][LDK];    // [t][n]
  __shared__ bf16 Bs[128][LDK];    // [d][n ^ ((d>>5)<<4)]
  const int bz = blockIdx.x;       // 0..63
  const int b = bz >> 3, chunk = bz & 7;
  const int d0 = blockIdx.y * 128;
  const int tid = threadIdx.x, wave = tid >> 6, lane = tid & 63;
  const int wm = (wave >> 1) * 64, wn = (wave & 1) * 64;

  f32x4 acc[4][4];
#pragma unroll
  for (int i = 0; i < 4; ++i)
#pragma unroll
    for (int j = 0; j < 4; ++j) acc[i][j] = (f32x4){0.f, 0.f, 0.f, 0.f};

  const int at = tid >> 1, anc = (tid & 1) * 32;
  const int bn = tid >> 2, bq = tid & 3, bdc = bq * 32;
  const int bcol = bn ^ (bq << 4);
  const long dwt_b = (long)b * 128 * 4096;
  const long x_b   = (long)b * 4096 * 1024;

  for (int k0 = 0; k0 < 512; k0 += 64) {
    const int nbase = chunk * 512 + k0;
    const bf16* ap = DWT + dwt_b + (long)at * 4096 + nbase + anc;
    *(bf16x8*)&As[at][anc + 0]  = *(const bf16x8*)(ap + 0);
    *(bf16x8*)&As[at][anc + 8]  = *(const bf16x8*)(ap + 8);
    *(bf16x8*)&As[at][anc + 16] = *(const bf16x8*)(ap + 16);
    *(bf16x8*)&As[at][anc + 24] = *(const bf16x8*)(ap + 24);
    const bf16* xp = Xbf + x_b + (long)(nbase + bn) * 1024 + d0 + bdc;
    bf16x8 q0 = *(const bf16x8*)(xp + 0);
    bf16x8 q1 = *(const bf16x8*)(xp + 8);
    bf16x8 q2 = *(const bf16x8*)(xp + 16);
    bf16x8 q3 = *(const bf16x8*)(xp + 24);
#pragma unroll
    for (int i = 0; i < 8; ++i) {
      Bs[bdc + i][bcol]      = q0[i];
      Bs[bdc + 8 + i][bcol]  = q1[i];
      Bs[bdc + 16 + i][bcol] = q2[i];
      Bs[bdc + 24 + i][bcol] = q3[i];
    }
    __syncthreads();
#pragma unroll
    for (int kk = 0; kk < 64; kk += 32) {
      bf16x8 af[4], bfr[4];
#pragma unroll
      for (int m = 0; m < 4; ++m) af[m]  = ldsfrag(&As[wm + m * 16][kk]);
#pragma unroll
      for (int n = 0; n < 4; ++n) bfr[n] = ldsfragB(Bs, wn + n * 16, kk);
#pragma unroll
      for (int m = 0; m < 4; ++m)
#pragma unroll
        for (int n = 0; n < 4; ++n)
          acc[m][n] = MFMA16(af[m], bfr[n], acc[m][n]);
    }
    __syncthreads();
  }
  const int cc = lane & 15, rr = (lane >> 4) * 4;
  bf16* Cp = Part + ((long)chunk * 8 + b) * 128 * 1024;
#pragma unroll
  for (int m = 0; m < 4; ++m)
#pragma unroll
    for (int n = 0; n < 4; ++n)
#pragma unroll
      for (int j = 0; j < 4; ++j)
        Cp[(long)(wm + m * 16 + rr + j) * 1024 + d0 + wn + n * 16 + cc] =
            (bf16)acc[m][n][j];
}

__global__ void k_reduce8(const bf16* __restrict__ P, bf16* __restrict__ O)
{
  long base = ((long)blockIdx.x * 256 + threadIdx.x) * 8;
  f32x4 slo = (f32x4){0.f,0.f,0.f,0.f}, shi = (f32x4){0.f,0.f,0.f,0.f};
#pragma unroll
  for (int c = 0; c < 8; ++c) {
    bf16x8 v = *(const bf16x8*)(P + (long)c * 1048576 + base);
#pragma unroll
    for (int j = 0; j < 4; ++j) { slo[j] += (float)v[j]; shi[j] += (float)v[4 + j]; }
  }
  bf16x8 o;
#pragma unroll
  for (int j = 0; j < 4; ++j) { o[j] = (bf16)slo[j]; o[4 + j] = (bf16)shi[j]; }
  *(bf16x8*)(O + base) = o;
}

// ---------------------------------------------------------------------------
// per-expert MLP layer: M=16 rows, N=1024(h) tiled 64, K=1024; weights fp32.
// BK=128 (proven r9). INL=0: A rows at (b*128+e*2+s); INL=1: compact.
// ---------------------------------------------------------------------------
template<int GELU, int INL>
__global__ __launch_bounds__(256) void k_expert(
    const bf16* __restrict__ Ab, const float* __restrict__ W,
    const float* __restrict__ bias, bf16* __restrict__ Out)
{
  __shared__ bf16 As[16][LDK2];
  __shared__ bf16 Bs[64][LDK2];
  const int e = blockIdx.y;
  const int h0 = blockIdx.x * 64;
  const int tid = threadIdx.x, wave = tid >> 6, lane = tid & 63;
  f32x4 acc = (f32x4){0.f, 0.f, 0.f, 0.f};

  const int hr = tid >> 2, kc = (tid & 3) * 32;
  const int ar = tid >> 4, akc = (tid & 15) * 8;
  const long arow = (INL == 0) ? (long)((ar >> 1) * 128 + e * 2 + (ar & 1))
                               : (long)(e * 16 + ar);

  for (int k0 = 0; k0 < 1024; k0 += 128) {
    *(bf16x8*)&As[ar][akc] = *(const bf16x8*)(Ab + arow * 1024 + k0 + akc);
    const float* wp = W + ((long)e * 1024 + h0 + hr) * 1024 + k0 + kc;
    float4 w0 = *(const float4*)(wp + 0);
    float4 w1 = *(const float4*)(wp + 4);
    float4 w2 = *(const float4*)(wp + 8);
    float4 w3 = *(const float4*)(wp + 12);
    float4 w4 = *(const float4*)(wp + 16);
    float4 w5 = *(const float4*)(wp + 20);
    float4 w6 = *(const float4*)(wp + 24);
    float4 w7 = *(const float4*)(wp + 28);
    *(bf16x8*)&Bs[hr][kc]      = cvt8(w0, w1);
    *(bf16x8*)&Bs[hr][kc + 8]  = cvt8(w2, w3);
    *(bf16x8*)&Bs[hr][kc + 16] = cvt8(w4, w5);
    *(bf16x8*)&Bs[hr][kc + 24] = cvt8(w6, w7);
    __syncthreads();
#pragma unroll
    for (int kk = 0; kk < 128; kk += 32) {
      bf16x8 a0 = ldsfrag2(&As[0][kk]);
      bf16x8 b0 = ldsfrag2(&Bs[wave * 16][kk]);
      acc = MFMA16(a0, b0, acc);
    }
    __syncthreads();
  }
  const int cc = lane & 15, rr = (lane >> 4) * 4;
  const int h = h0 + wave * 16 + cc;
  const float bs = bias[e * 1024 + h];
#pragma unroll
  for (int j = 0; j < 4; ++j) {
    float v = acc[j] + bs;
    if (GELU) {
      float x3 = v * v * v;
      v = 0.5f * v * (1.f + tanhf(0.7978845608028654f * (v + 0.044715f * x3)));
    }
    int m = rr + j;
    long orow = (INL == 0) ? (long)(e * 16 + m) : (long)((m >> 1) * 128 + e * 2 + (m & 1));
    Out[orow * 1024 + h] = (bf16)v;
  }
}

// ---------------------------------------------------------------------------
// projT[o][bt] = sum_d out_w_bf[o][d] * outs_bf[bt][d]   (1024x1024x1024)
// BM=BN=64, 4 waves (32x32 each)
// ---------------------------------------------------------------------------
__global__ __launch_bounds__(256) void k_proj(
    const bf16* __restrict__ OWbf, const bf16* __restrict__ OS, bf16* __restrict__ PT)
{
  __shared__ bf16 As[64][LDK];
  __shared__ bf16 Bs[64][LDK];
  const int o0 = blockIdx.y * 64, t0 = blockIdx.x * 64;
  const int tid = threadIdx.x, wave = tid >> 6, lane = tid & 63;
  const int wm = (wave >> 1) * 32, wn = (wave & 1) * 32;
  f32x4 acc[2][2];
#pragma unroll
  for (int i = 0; i < 2; ++i)
#pragma unroll
    for (int j = 0; j < 2; ++j) acc[i][j] = (f32x4){0.f, 0.f, 0.f, 0.f};

  const int r = tid >> 2, kc = (tid & 3) * 16;
  for (int k0 = 0; k0 < 1024; k0 += 64) {
    const bf16* apo = OWbf + (long)(o0 + r) * 1024 + k0 + kc;
    *(bf16x8*)&As[r][kc]     = *(const bf16x8*)(apo + 0);
    *(bf16x8*)&As[r][kc + 8] = *(const bf16x8*)(apo + 8);
    const bf16* bpo = OS + (long)(t0 + r) * 1024 + k0 + kc;
    *(bf16x8*)&Bs[r][kc]     = *(const bf16x8*)(bpo + 0);
    *(bf16x8*)&Bs[r][kc + 8] = *(const bf16x8*)(bpo + 8);
    __syncthreads();
#pragma unroll
    for (int kk = 0; kk < 64; kk += 32) {
      bf16x8 a0 = ldsfrag(&As[wm][kk]);
      bf16x8 a1 = ldsfrag(&As[wm + 16][kk]);
      bf16x8 b0 = ldsfrag(&Bs[wn][kk]);
      bf16x8 b1 = ldsfrag(&Bs[wn + 16][kk]);
      acc[0][0] = MFMA16(a0, b0, acc[0][0]);
      acc[0][1] = MFMA16(a0, b1, acc[0][1]);
      acc[1][0] = MFMA16(a1, b0, acc[1][0]);
      acc[1][1] = MFMA16(a1, b1, acc[1][1]);
    }
    __syncthreads();
  }
  const int cc = lane & 15, rr = (lane >> 4) * 4;
#pragma unroll
  for (int m = 0; m < 2; ++m)
#pragma unroll
    for (int n = 0; n < 2; ++n)
#pragma unroll
      for (int j = 0; j < 4; ++j)
        PT[(long)(o0 + wm + m * 16 + rr + j) * 1024 + t0 + wn + n * 16 + cc] =
            (bf16)acc[m][n][j];
}

// ---------------------------------------------------------------------------
// out[b][n][o] = sum_t CW[b][n][t] * PT[o][b*128+t] + out_b[o]; also aux=0.
// per b: M=4096, N=1024, K=128; BM=128, BN=128, BK=64.
// GRID: x=m0 (32), y=o0 (8), z=b — blocks sharing a CW A-tile (varying o0)
// are stride-32 apart => same XCD => CW tile L2-shared (r12-proven).
// ---------------------------------------------------------------------------
__global__ __launch_bounds__(256) void k_combine(
    const bf16* __restrict__ CW, const bf16* __restrict__ PT,
    const float* __restrict__ ob, float* __restrict__ O)
{
  __shared__ bf16 As[128][LDK];
  __shared__ bf16 Bs[128][LDK];
  const int b = blockIdx.z, m0 = blockIdx.x * 128, o0 = blockIdx.y * 128;
  const int tid = threadIdx.x, wave = tid >> 6, lane = tid & 63;
  const int wm = (wave >> 1) * 64, wn = (wave & 1) * 64;

  if (blockIdx.x == 0 && blockIdx.y == 0 && blockIdx.z == 0 && tid == 0)
    O[(long)B_ * N_ * D_] = 0.f;   // aux loss scalar

  f32x4 acc[4][4];
#pragma unroll
  for (int i = 0; i < 4; ++i)
#pragma unroll
    for (int j = 0; j < 4; ++j) acc[i][j] = (f32x4){0.f, 0.f, 0.f, 0.f};

  const int r = tid >> 1, tc = (tid & 1) * 32;
  for (int k0 = 0; k0 < 128; k0 += 64) {
    const bf16* ap = CW + ((long)b * N_ + m0 + r) * 128 + k0 + tc;
    *(bf16x8*)&As[r][tc + 0]  = *(const bf16x8*)(ap + 0);
    *(bf16x8*)&As[r][tc + 8]  = *(const bf16x8*)(ap + 8);
    *(bf16x8*)&As[r][tc + 16] = *(const bf16x8*)(ap + 16);
    *(bf16x8*)&As[r][tc + 24] = *(const bf16x8*)(ap + 24);
    const bf16* bp = PT + (long)(o0 + r) * 1024 + b * 128 + k0 + tc;
    *(bf16x8*)&Bs[r][tc + 0]  = *(const bf16x8*)(bp + 0);
    *(bf16x8*)&Bs[r][tc + 8]  = *(const bf16x8*)(bp + 8);
    *(bf16x8*)&Bs[r][tc + 16] = *(const bf16x8*)(bp + 16);
    *(bf16x8*)&Bs[r][tc + 24] = *(const bf16x8*)(bp + 24);
    __syncthreads();
#pragma unroll
    for (int kk = 0; kk < 64; kk += 32) {
      bf16x8 af[4], bfr[4];
#pragma unroll
      for (int m = 0; m < 4; ++m) af[m]  = ldsfrag(&As[wm + m * 16][kk]);
#pragma unroll
      for (int n = 0; n < 4; ++n) bfr[n] = ldsfrag(&Bs[wn + n * 16][kk]);
#pragma unroll
      for (int m = 0; m < 4; ++m)
#pragma unroll
        for (int n = 0; n < 4; ++n)
          acc[m][n] = MFMA16(af[m], bfr[n], acc[m][n]);
    }
    __syncthreads();
  }
  const int cc = lane & 15, rr = (lane >> 4) * 4;
#pragma unroll
  for (int n = 0; n < 4; ++n) {
    const int o = o0 + wn + n * 16 + cc;
    const float bv = ob[o];
#pragma unroll
    for (int m = 0; m < 4; ++m)
#pragma unroll
      for (int j = 0; j < 4; ++j)
        O[((long)b * N_ + m0 + wm + m * 16 + rr + j) * 1024 + o] = acc[m][n][j] + bv;
  }
}

// ---------------------------------------------------------------------------
extern "C" void kernel_launch(void* const* d_in, const int* in_sizes, int n_in,
                              void* d_out, int out_size, void* d_ws, size_t ws_size,
                              hipStream_t stream)
{
  const float* x     = (const float*)d_in[0];
  const float* phi_w = (const float*)d_in[1];
  const float* fc1_w = (const float*)d_in[2];
  const float* fc1_b = (const float*)d_in[3];
  const float* fc2_w = (const float*)d_in[4];
  const float* fc2_b = (const float*)d_in[5];
  const float* out_w = (const float*)d_in[6];
  const float* out_b = (const float*)d_in[7];
  float* out = (float*)d_out;

  float* ws     = (float*)d_ws;
  float* logits = ws;                         // 4,194,304 f
  float* redM   = logits + 4194304;           // 65,536 (512 chunks x 128)
  float* redS   = redM + 65536;               // 65,536
  float* Mf     = redS + 65536;               // 1,024
  float* Zf     = Mf + 1024;                  // 1,024
  bf16* DWT     = (bf16*)(Zf + 1024);         // 4,194,304 bf16
  bf16* CW      = DWT + 4194304;              // 4,194,304 bf16
  bf16* slots   = CW + 4194304;               // 1,048,576 bf16
  bf16* hbuf    = slots + 1048576;            // 1,048,576 bf16
  bf16* outs    = hbuf + 1048576;             // 1,048,576 bf16
  bf16* projT   = outs + 1048576;             // 1,048,576 bf16
  bf16* phi_bf  = projT + 1048576;            // 131,072 bf16
  bf16* outw_bf = phi_bf + 131072;            // 1,048,576 bf16

  // scratch in d_out (dead until k_combine writes it):
  bf16* Xbf   = (bf16*)d_out;                 // 33,554,432 bf16 = 64 MB
  bf16* Part  = Xbf + 33554432;               // 8 x 1,048,576 bf16 = 16 MB

  k_convert<<<dim3(1152), 256, 0, stream>>>(phi_w, out_w, phi_bf, outw_bf);
  k_logits<<<dim3(512), 256, 0, stream>>>(x, phi_bf, logits, Xbf, CW, redM, redS);
  disp_final<<<dim3(4), 256, 0, stream>>>(redM, redS, Mf, Zf);
  k_dwt<<<dim3(64, 8), 256, 0, stream>>>(logits, Mf, Zf, DWT);
  k_slots<<<dim3(64, 8), 256, 0, stream>>>(DWT, Xbf, Part);
  k_reduce8<<<dim3(512), 256, 0, stream>>>(Part, slots);
  k_expert<1, 0><<<dim3(16, 64), 256, 0, stream>>>(slots, fc1_w, fc1_b, hbuf);
  k_expert<0, 1><<<dim3(16, 64), 256, 0, stream>>>(hbuf, fc2_w, fc2_b, outs);
  k_proj<<<dim3(16, 16), 256, 0, stream>>>(outw_bf, outs, projT);
  k_combine<<<dim3(32, 8, 8), 256, 0, stream>>>(CW, projT, out_b, out);
}